// Round 12
// baseline (275.599 us; speedup 1.0000x reference)
//
#include <hip/hip_runtime.h>

// ACE symmetrizer, fused: b[r,f,n] = sum_m cg[r,m] * A[f,m,n] for 5 (A, CG0, CG1)
// groups in ONE kernel. Memory-bound: ~500MB read + 537MB write -> ~165us floor.
//
// Round-12 = round-7 (207us, best) with ONE change: bijective grid-index
// permutation t = (bid%1024)*8 + bid/1024. Co-resident blocks on a CU
// (b, b+256, b+512, b+768) now land in DIFFERENT op segments (M=49/45/25/9)
// -> different phase lengths -> end-of-block store bursts desynchronize.
// Segmented heavy-first ordering phase-locked ~1024 identical blocks, making
// the device oscillate between read epochs and write-burst epochs (HBM
// direction-turnaround + peak-demand cost). Also self-balances the tail.

typedef float f32x2 __attribute__((ext_vector_type(2)));

#define NN 1024

// output float offsets (return order: b0 x5 then b1 x5)
#define O0_0 0UL
#define O0_1 8388608UL
#define O0_2 16777216UL
#define O0_3 25165824UL
#define O0_4 29360128UL
#define O1_0 33554432UL
#define O1_1 58720256UL
#define O1_2 83886080UL
#define O1_3 109051904UL
#define O1_4 121634816UL

// padded cgT float offsets in ws: 32*MP per op, MP = {12,28,52,28,48}
#define WP_0 0
#define WP_1 384
#define WP_2 1280
#define WP_3 2944
#define WP_4 3840
#define WP_TOT 5376

__global__ __launch_bounds__(256)
void cg_transpose(const float* __restrict__ c00, const float* __restrict__ c01,
                  const float* __restrict__ c02, const float* __restrict__ c03,
                  const float* __restrict__ c04,
                  const float* __restrict__ c10, const float* __restrict__ c11,
                  const float* __restrict__ c12, const float* __restrict__ c13,
                  const float* __restrict__ c14,
                  float* __restrict__ w)
{
    int t = blockIdx.x * 256 + threadIdx.x;
    if (t >= WP_TOT) return;
    int M, off; const float* g0; const float* g1;
    if      (t < WP_1) { M = 9;  off = WP_0; g0 = c00; g1 = c10; }
    else if (t < WP_2) { M = 25; off = WP_1; g0 = c01; g1 = c11; }
    else if (t < WP_3) { M = 49; off = WP_2; g0 = c02; g1 = c12; }
    else if (t < WP_4) { M = 27; off = WP_3; g0 = c03; g1 = c13; }
    else               { M = 45; off = WP_4; g0 = c04; g1 = c14; }
    int loc = t - off;
    int m = loc >> 5, r = loc & 31;
    float v = 0.f;
    if (m < M) v = (r < 8) ? g0[r * M + m] : g1[(r - 8) * M + m];
    w[t] = v;
}

template<int M, int MP>
__device__ __forceinline__ void run_op(const float* __restrict__ Af,  // A + f*M*NN + n0
                                       const float* __restrict__ cg,  // cgT + WP_op, [MP][32]
                                       float* __restrict__ p0,        // out + o0 + f*NN + n0
                                       float* __restrict__ p1,        // out + o1 + f*NN + n0
                                       size_t stride)                 // F*NN
{
    const f32x2* ap = reinterpret_cast<const f32x2*>(Af);

    f32x2 buf[4];
#pragma unroll
    for (int i = 0; i < 4; ++i) {
        const int mi = (i < M) ? i : (M - 1);
        buf[i] = __builtin_nontemporal_load(ap + (size_t)mi * (NN / 2));
    }

    f32x2 acc[32];
#pragma unroll
    for (int r = 0; r < 32; ++r) acc[r] = (f32x2)(0.f);

#pragma unroll 1
    for (int m = 0; m < MP; m += 4) {
#pragma unroll
        for (int i = 0; i < 4; ++i) {
            const f32x2 cur = buf[i];
            int nm = m + 4 + i;
            nm = (nm < M) ? nm : (M - 1);            // clamped prefetch
            buf[i] = __builtin_nontemporal_load(ap + (size_t)nm * (NN / 2));
            const float* c = cg + (size_t)(m + i) * 32;   // uniform -> s_load x2
#pragma unroll
            for (int r = 0; r < 32; ++r) {
                const float cr = c[r];
                acc[r].x = fmaf(cr, cur.x, acc[r].x);
                acc[r].y = fmaf(cr, cur.y, acc[r].y);
            }
        }
    }

#pragma unroll
    for (int r = 0; r < 8; ++r)
        __builtin_nontemporal_store(acc[r], reinterpret_cast<f32x2*>(p0 + r * stride));
#pragma unroll
    for (int r = 0; r < 24; ++r)
        __builtin_nontemporal_store(acc[8 + r], reinterpret_cast<f32x2*>(p1 + r * stride));
}

__global__ __launch_bounds__(256)
void ace_sym_all(const float* __restrict__ A0, const float* __restrict__ A1,
                 const float* __restrict__ A2, const float* __restrict__ A3,
                 const float* __restrict__ A4,
                 const float* __restrict__ cgT, float* __restrict__ out)
{
    // Bijective permutation over 8192 = 1024*8: co-resident blocks (bid
    // differing by 256) decode to tiles ~2048 apart -> different op segments
    // -> desynchronized store bursts on every CU.
    const int bid = (((int)blockIdx.x & 1023) << 3) | ((int)blockIdx.x >> 10);
    // block covers 512 n: half = bid&1 selects n in [0,512) or [512,1024)
    const int n0base = (int)threadIdx.x * 2;

    if (bid < 2048) {
        const size_t f = bid >> 1;
        const int n0 = ((bid & 1) << 9) + n0base;
        run_op<49, 52>(A2 + f * 49 * NN + n0, cgT + WP_2,
                       out + O0_2 + f * NN + n0, out + O1_2 + f * NN + n0,
                       (size_t)1024 * NN);
    } else if (bid < 3072) {
        const int loc = bid - 2048;
        const size_t f = loc >> 1;
        const int n0 = ((loc & 1) << 9) + n0base;
        run_op<45, 48>(A4 + f * 45 * NN + n0, cgT + WP_4,
                       out + O0_4 + f * NN + n0, out + O1_4 + f * NN + n0,
                       (size_t)512 * NN);
    } else if (bid < 5120) {
        const int loc = bid - 3072;
        const size_t f = loc >> 1;
        const int n0 = ((loc & 1) << 9) + n0base;
        run_op<25, 28>(A1 + f * 25 * NN + n0, cgT + WP_1,
                       out + O0_1 + f * NN + n0, out + O1_1 + f * NN + n0,
                       (size_t)1024 * NN);
    } else if (bid < 6144) {
        const int loc = bid - 5120;
        const size_t f = loc >> 1;
        const int n0 = ((loc & 1) << 9) + n0base;
        run_op<27, 28>(A3 + f * 27 * NN + n0, cgT + WP_3,
                       out + O0_3 + f * NN + n0, out + O1_3 + f * NN + n0,
                       (size_t)512 * NN);
    } else {
        const int loc = bid - 6144;
        const size_t f = loc >> 1;
        const int n0 = ((loc & 1) << 9) + n0base;
        run_op<9, 12>(A0 + f * 9 * NN + n0, cgT + WP_0,
                      out + O0_0 + f * NN + n0, out + O1_0 + f * NN + n0,
                      (size_t)1024 * NN);
    }
}

extern "C" void kernel_launch(void* const* d_in, const int* in_sizes, int n_in,
                              void* d_out, int out_size, void* d_ws, size_t ws_size,
                              hipStream_t stream)
{
    const float* A0 = (const float*)d_in[0];
    const float* A1 = (const float*)d_in[1];
    const float* A2 = (const float*)d_in[2];
    const float* A3 = (const float*)d_in[3];
    const float* A4 = (const float*)d_in[4];

    float* wsT = (float*)d_ws;

    hipLaunchKernelGGL(cg_transpose, dim3((WP_TOT + 255) / 256), dim3(256), 0, stream,
                       (const float*)d_in[5], (const float*)d_in[6], (const float*)d_in[7],
                       (const float*)d_in[8], (const float*)d_in[9],
                       (const float*)d_in[10], (const float*)d_in[11], (const float*)d_in[12],
                       (const float*)d_in[13], (const float*)d_in[14], wsT);

    hipLaunchKernelGGL(ace_sym_all, dim3(8192), dim3(256), 0, stream,
                       A0, A1, A2, A3, A4, (const float*)wsT, (float*)d_out);
}

// Round 13
// 205.678 us; speedup vs baseline: 1.3400x; 1.3400x over previous
//
#include <hip/hip_runtime.h>

// ACE symmetrizer, fused: b[r,f,n] = sum_m cg[r,m] * A[f,m,n] for 5 (A, CG0, CG1)
// groups in ONE kernel. Memory-bound: ~500MB read + 537MB write -> ~165us floor.
//
// Round-13 = round-7 (207us, best) + LDS STORE-STAGING:
//  Round-12's A/B proved write-side DRAM page locality is worth ~70us.
//  Round-7 waves each keep 32 interleaved 512B write streams alive
//  (~32K streams device-wide >> DRAM open-page capacity). Here each block
//  stages 8 output rows in LDS (16KB), then each wave drains 2 FULL rows as
//  2x1KB dwordx4 nt stores -> one 2KB page-contiguous chunk per wave at a
//  time, ~8x fewer concurrent write streams. FMA loop, nt loads, segmented
//  heavy-first order: identical to round 7. ~100 VGPR + 16KB LDS -> still
//  4 blocks/CU (16 waves).

typedef float f32x2 __attribute__((ext_vector_type(2)));
typedef float f32x4 __attribute__((ext_vector_type(4)));

#define NN 1024

// output float offsets (return order: b0 x5 then b1 x5)
#define O0_0 0UL
#define O0_1 8388608UL
#define O0_2 16777216UL
#define O0_3 25165824UL
#define O0_4 29360128UL
#define O1_0 33554432UL
#define O1_1 58720256UL
#define O1_2 83886080UL
#define O1_3 109051904UL
#define O1_4 121634816UL

// padded cgT float offsets in ws: 32*MP per op, MP = {12,28,52,28,48}
#define WP_0 0
#define WP_1 384
#define WP_2 1280
#define WP_3 2944
#define WP_4 3840
#define WP_TOT 5376

__global__ __launch_bounds__(256)
void cg_transpose(const float* __restrict__ c00, const float* __restrict__ c01,
                  const float* __restrict__ c02, const float* __restrict__ c03,
                  const float* __restrict__ c04,
                  const float* __restrict__ c10, const float* __restrict__ c11,
                  const float* __restrict__ c12, const float* __restrict__ c13,
                  const float* __restrict__ c14,
                  float* __restrict__ w)
{
    int t = blockIdx.x * 256 + threadIdx.x;
    if (t >= WP_TOT) return;
    int M, off; const float* g0; const float* g1;
    if      (t < WP_1) { M = 9;  off = WP_0; g0 = c00; g1 = c10; }
    else if (t < WP_2) { M = 25; off = WP_1; g0 = c01; g1 = c11; }
    else if (t < WP_3) { M = 49; off = WP_2; g0 = c02; g1 = c12; }
    else if (t < WP_4) { M = 27; off = WP_3; g0 = c03; g1 = c13; }
    else               { M = 45; off = WP_4; g0 = c04; g1 = c14; }
    int loc = t - off;
    int m = loc >> 5, r = loc & 31;
    float v = 0.f;
    if (m < M) v = (r < 8) ? g0[r * M + m] : g1[(r - 8) * M + m];
    w[t] = v;
}

// One (op, f, n-half). FMA loop identical to round 7; store path goes
// through LDS so each wave writes full rows (2KB contiguous) one at a time.
template<int M, int MP>
__device__ __forceinline__ void run_op(const float* __restrict__ Af,  // A + f*M*NN + n0
                                       const float* __restrict__ cg,  // cgT + WP_op
                                       float* __restrict__ p0,        // out0 + f*NN + nblk
                                       float* __restrict__ p1,        // out1 + f*NN + nblk
                                       size_t stride,                 // F*NN
                                       float (*lds)[512],
                                       int tid)
{
    const f32x2* ap = reinterpret_cast<const f32x2*>(Af);

    f32x2 buf[4];
#pragma unroll
    for (int i = 0; i < 4; ++i) {
        const int mi = (i < M) ? i : (M - 1);
        buf[i] = __builtin_nontemporal_load(ap + (size_t)mi * (NN / 2));
    }

    f32x2 acc[32];
#pragma unroll
    for (int r = 0; r < 32; ++r) acc[r] = (f32x2)(0.f);

#pragma unroll 1
    for (int m = 0; m < MP; m += 4) {
#pragma unroll
        for (int i = 0; i < 4; ++i) {
            const f32x2 cur = buf[i];
            int nm = m + 4 + i;
            nm = (nm < M) ? nm : (M - 1);            // clamped prefetch
            buf[i] = __builtin_nontemporal_load(ap + (size_t)nm * (NN / 2));
            const float* c = cg + (size_t)(m + i) * 32;   // uniform -> s_load x2
#pragma unroll
            for (int r = 0; r < 32; ++r) {
                const float cr = c[r];
                acc[r].x = fmaf(cr, cur.x, acc[r].x);
                acc[r].y = fmaf(cr, cur.y, acc[r].y);
            }
        }
    }

    // --- LDS store-staging: 4 chunks x 8 rows --------------------------
    const int lane = tid & 63;
    const int wv   = tid >> 6;          // wave id 0..3; handles rows 2wv, 2wv+1
#pragma unroll
    for (int chunk = 0; chunk < 4; ++chunk) {
        __syncthreads();                 // previous chunk fully drained
#pragma unroll
        for (int rl = 0; rl < 8; ++rl) {
            const f32x2 v = acc[chunk * 8 + rl];
            lds[rl][2 * tid]     = v.x;
            lds[rl][2 * tid + 1] = v.y;
        }
        __syncthreads();
        // wave wv drains rows 2wv, 2wv+1 as 2x 1KB contiguous nt stores each
#pragma unroll
        for (int d = 0; d < 2; ++d) {
            const int rl = 2 * wv + d;
            float* rowp;
            if (chunk == 0)  rowp = p0 + (size_t)rl * stride;               // out0 rows 0..7
            else             rowp = p1 + (size_t)((chunk - 1) * 8 + rl) * stride; // out1 rows 0..23
            const f32x4* lrow = reinterpret_cast<const f32x4*>(lds[rl]);
#pragma unroll
            for (int p = 0; p < 2; ++p) {
                const f32x4 v4 = lrow[64 * p + lane];
                __builtin_nontemporal_store(v4,
                    reinterpret_cast<f32x4*>(rowp + 256 * p + 4 * lane));
            }
        }
    }
}

__global__ __launch_bounds__(256)
void ace_sym_all(const float* __restrict__ A0, const float* __restrict__ A1,
                 const float* __restrict__ A2, const float* __restrict__ A3,
                 const float* __restrict__ A4,
                 const float* __restrict__ cgT, float* __restrict__ out)
{
    __shared__ float lds[8][512];        // 16KB: one 8-row staging chunk

    const int bid = blockIdx.x;
    const int tid = (int)threadIdx.x;
    const int n0base = tid * 2;

    // heavy-first: M=49 (F=1024), M=45 (512), M=25 (1024), M=27 (512), M=9 (1024)
    if (bid < 2048) {
        const size_t f = bid >> 1;
        const int nblk = (bid & 1) << 9;
        run_op<49, 52>(A2 + f * 49 * NN + nblk + n0base, cgT + WP_2,
                       out + O0_2 + f * NN + nblk, out + O1_2 + f * NN + nblk,
                       (size_t)1024 * NN, lds, tid);
    } else if (bid < 3072) {
        const int loc = bid - 2048;
        const size_t f = loc >> 1;
        const int nblk = (loc & 1) << 9;
        run_op<45, 48>(A4 + f * 45 * NN + nblk + n0base, cgT + WP_4,
                       out + O0_4 + f * NN + nblk, out + O1_4 + f * NN + nblk,
                       (size_t)512 * NN, lds, tid);
    } else if (bid < 5120) {
        const int loc = bid - 3072;
        const size_t f = loc >> 1;
        const int nblk = (loc & 1) << 9;
        run_op<25, 28>(A1 + f * 25 * NN + nblk + n0base, cgT + WP_1,
                       out + O0_1 + f * NN + nblk, out + O1_1 + f * NN + nblk,
                       (size_t)1024 * NN, lds, tid);
    } else if (bid < 6144) {
        const int loc = bid - 5120;
        const size_t f = loc >> 1;
        const int nblk = (loc & 1) << 9;
        run_op<27, 28>(A3 + f * 27 * NN + nblk + n0base, cgT + WP_3,
                       out + O0_3 + f * NN + nblk, out + O1_3 + f * NN + nblk,
                       (size_t)512 * NN, lds, tid);
    } else {
        const int loc = bid - 6144;
        const size_t f = loc >> 1;
        const int nblk = (loc & 1) << 9;
        run_op<9, 12>(A0 + f * 9 * NN + nblk + n0base, cgT + WP_0,
                      out + O0_0 + f * NN + nblk, out + O1_0 + f * NN + nblk,
                      (size_t)1024 * NN, lds, tid);
    }
}

extern "C" void kernel_launch(void* const* d_in, const int* in_sizes, int n_in,
                              void* d_out, int out_size, void* d_ws, size_t ws_size,
                              hipStream_t stream)
{
    const float* A0 = (const float*)d_in[0];
    const float* A1 = (const float*)d_in[1];
    const float* A2 = (const float*)d_in[2];
    const float* A3 = (const float*)d_in[3];
    const float* A4 = (const float*)d_in[4];

    float* wsT = (float*)d_ws;

    hipLaunchKernelGGL(cg_transpose, dim3((WP_TOT + 255) / 256), dim3(256), 0, stream,
                       (const float*)d_in[5], (const float*)d_in[6], (const float*)d_in[7],
                       (const float*)d_in[8], (const float*)d_in[9],
                       (const float*)d_in[10], (const float*)d_in[11], (const float*)d_in[12],
                       (const float*)d_in[13], (const float*)d_in[14], wsT);

    hipLaunchKernelGGL(ace_sym_all, dim3(8192), dim3(256), 0, stream,
                       A0, A1, A2, A3, A4, (const float*)wsT, (float*)d_out);
}